// Round 1
// baseline (31.503 us; speedup 1.0000x reference)
//
#include <hip/hip_runtime.h>
#include <hip/hip_bf16.h>

// LengthRegulator: out[b, j, :] = x[b, idx[b,j], :] where idx comes from
// rounding dur, prefix-summing, and interval-inverting (searchsorted right).
// B=16, T=1024, D=384, T_OUT=4096 (fixed by the reference).

#define LR_B     16
#define LR_T     1024
#define LR_D     384
#define LR_TOUT  4096
#define LR_D4    (LR_D / 4)   // 96 float4 per row

// Kernel A: one block per batch row. Round durations, inclusive scan in LDS,
// scatter-expand token intervals into idx[B][T_OUT] (in d_ws).
__global__ __launch_bounds__(LR_T) void lr_scan_expand(
    const float* __restrict__ dur, int* __restrict__ idx) {
    const int b = blockIdx.x;
    const int t = threadIdx.x;

    __shared__ int s[LR_T];

    float d = dur[b * LR_T + t];
    d = fmaxf(d, 0.0f);
    const int c = (int)floorf(d + 0.5f);
    s[t] = c;
    __syncthreads();

    // Hillis-Steele inclusive scan over T=1024 (10 steps).
    #pragma unroll
    for (int off = 1; off < LR_T; off <<= 1) {
        int v = (t >= off) ? s[t - off] : 0;
        __syncthreads();
        s[t] += v;
        __syncthreads();
    }

    int end   = s[t];
    int start = end - c;
    // Robust clamp (sums are exactly T_OUT by construction, but be safe).
    start = min(start, LR_TOUT);
    end   = min(end, LR_TOUT);
    int* row_idx = idx + b * LR_TOUT;
    for (int p = start; p < end; ++p) row_idx[p] = t;

    // Tail: positions >= total map to T (clipped to T-1).
    const int total = min(s[LR_T - 1], LR_TOUT);
    for (int p = total + t; p < LR_TOUT; p += LR_T) row_idx[p] = LR_T - 1;
}

// Kernel B: pure gather. One block = 4 output rows, 96 float4 lanes per row.
// Stores are block-contiguous; loads are 1536B coalesced segments.
__global__ __launch_bounds__(384) void lr_gather(
    const float4* __restrict__ x, const int* __restrict__ idx,
    float4* __restrict__ out) {
    const int tid = threadIdx.x;
    const int row_local = tid / LR_D4;   // 0..3
    const int d = tid - row_local * LR_D4;

    const int orow = blockIdx.x * 4 + row_local;     // global output row, < B*T_OUT
    const int b = orow >> 12;                        // orow / 4096
    const int t = idx[orow];

    out[orow * LR_D4 + d] = x[(b * LR_T + t) * LR_D4 + d];
}

extern "C" void kernel_launch(void* const* d_in, const int* in_sizes, int n_in,
                              void* d_out, int out_size, void* d_ws, size_t ws_size,
                              hipStream_t stream) {
    const float* x   = (const float*)d_in[0];   // [B, T, D] fp32
    const float* dur = (const float*)d_in[1];   // [B, T]    fp32
    // d_in[2] = out_len scalar (known: 4096)

    int* idx = (int*)d_ws;                      // B*T_OUT ints = 256 KiB

    lr_scan_expand<<<LR_B, LR_T, 0, stream>>>(dur, idx);

    const int nblocks = (LR_B * LR_TOUT) / 4;   // 16384
    lr_gather<<<nblocks, 384, 0, stream>>>(
        (const float4*)x, idx, (float4*)d_out);
}

// Round 2
// 28.893 us; speedup vs baseline: 1.0903x; 1.0903x over previous
//
#include <hip/hip_runtime.h>
#include <hip/hip_bf16.h>

// LengthRegulator: out[b, j, :] = x[b, tok(j), :], where tok(j) is the token
// whose rounded-duration cumulative interval contains j.
// Inverted formulation: one block per input token broadcast-writes its x row
// into its output interval [csum[t-1], csum[t]) -> x is read from HBM exactly
// once (25 MB), writes are the compulsory 100.7 MB.
// B=16, T=1024, D=384, T_OUT=4096 (fixed by the reference).

#define LR_B     16
#define LR_T     1024
#define LR_D4    96      // 384 floats = 96 float4 per row
#define LR_TOUT  4096

// Kernel A: one block per batch row. Round durations, inclusive scan via
// wave shfl (6 steps) + cross-wave scan of 16 partials (2 barriers total).
__global__ __launch_bounds__(LR_T) void lr_scan(
    const float* __restrict__ dur, int* __restrict__ csum) {
    const int b    = blockIdx.x;
    const int t    = threadIdx.x;
    const int lane = t & 63;
    const int wid  = t >> 6;

    float d = fmaxf(dur[b * LR_T + t], 0.0f);
    int v = (int)floorf(d + 0.5f);

    // Inclusive scan within the 64-lane wave.
    #pragma unroll
    for (int off = 1; off < 64; off <<= 1) {
        int u = __shfl_up(v, off, 64);
        if (lane >= off) v += u;
    }

    __shared__ int wsum[16];
    if (lane == 63) wsum[wid] = v;
    __syncthreads();

    // Wave 0, lanes 0..15: inclusive scan of the 16 wave sums.
    if (wid == 0 && lane < 16) {
        int w = wsum[lane];
        #pragma unroll
        for (int off = 1; off < 16; off <<= 1) {
            int u = __shfl_up(w, off, 64);
            if (lane >= off) w += u;
        }
        wsum[lane] = w;   // inclusive
    }
    __syncthreads();

    const int offset = (wid == 0) ? 0 : wsum[wid - 1];
    csum[b * LR_T + t] = v + offset;
}

// Kernel B: one block per (b, t) input token. 384 threads = 96 float4 lanes
// x 4 row-slot groups. Read the x row once, store it to each output row in
// [start, end) as fully-coalesced 1536B segments.
__global__ __launch_bounds__(384) void lr_write(
    const float4* __restrict__ x, const int* __restrict__ csum,
    float4* __restrict__ out) {
    const int blk = blockIdx.x;          // b * T + t
    const int b   = blk >> 10;
    const int t   = blk & (LR_T - 1);
    const int tid = threadIdx.x;
    const int g   = tid / LR_D4;         // 0..3
    const int d   = tid - g * LR_D4;

    const int* cs = csum + b * LR_T;
    int end   = min(cs[t], LR_TOUT);
    int start = (t == 0) ? 0 : min(cs[t - 1], LR_TOUT);
    // Tail positions >= total map to token T-1 (searchsorted + clip).
    if (t == LR_T - 1) end = LR_TOUT;
    if (start >= end) return;

    const float4 v = x[(b * LR_T + t) * LR_D4 + d];
    float4* orow = out + (size_t)b * LR_TOUT * LR_D4 + d;
    for (int p = start + g; p < end; p += 4)
        orow[p * LR_D4] = v;
}

extern "C" void kernel_launch(void* const* d_in, const int* in_sizes, int n_in,
                              void* d_out, int out_size, void* d_ws, size_t ws_size,
                              hipStream_t stream) {
    const float* x   = (const float*)d_in[0];   // [B, T, D] fp32
    const float* dur = (const float*)d_in[1];   // [B, T]    fp32
    // d_in[2] = out_len scalar (known: 4096)

    int* csum = (int*)d_ws;                     // B*T ints = 64 KiB

    lr_scan<<<LR_B, LR_T, 0, stream>>>(dur, csum);
    lr_write<<<LR_B * LR_T, 384, 0, stream>>>(
        (const float4*)x, csum, (float4*)d_out);
}